// Round 11
// baseline (264.556 us; speedup 1.0000x reference)
//
#include <hip/hip_runtime.h>

// Trilinear forward-splat, corner-basis LDS accumulation, 4x16-bit packed u64
// atomics (2 DS atomics/voxel).
// R10->R11: (a) revert to 8x8x32 chunk (BK=32: 128B-contiguous loads, 144B
// flush rows — R10's BK=16 doubled FETCH and 2.4x'd WRITE); (b) fields are the
// 4 yz-corner weights (F_A..F_D) instead of moments -> flush takes ONE field
// per covering bin; (c) cheap lo/hi 32-bit borrow-corrected pack/decode;
// (d) dead bins trimmed (b=TJ-1, c=TK-1 never written): 12x11x35 = 36.96 KB.
// Reference semantics (exact):
//   locs = max(grid + flow, 0)
//   delta = locs - floor(locs)           (from UNclamped floor)
//   base  = min((int)floor(locs), dim-1)
//   corner per axis = min(base + {0,1}, dim-1)   (collapsed corners add twice)
//
// Per x-corner deposit into bin (a,b0,c0), fields scale 2^9 fixed-point:
//   F_A=w(1-dy)(1-dz) -> cell(b0,c0);     F_B=w*dy(1-dz) -> cell(b0+1,c0)
//   F_C=w(1-dy)dz     -> cell(b0,c0+1);   F_D=w*dy*dz    -> cell(b0+1,c0+1)
// cell(b,z) = e0[bin(b,z)] + e1[bin(b-1,z)] + e2[bin(b,z-1)] + e3[bin(b-1,z-1)]
// Modular u64 sums exact while |field sum| < 2^15 and |lo-word sum| < 2^31
// (fields strictly smaller than R9's validated M00).

constexpr int H = 192, W = 192, Dd = 192;
constexpr int N = H * W * Dd;
constexpr int WD = W * Dd;

constexpr int BI = 8, BJ = 8, BK = 32;       // source chunk per block (2048 voxels)
constexpr int HL = 2;                        // halo radius
constexpr int TI = BI + 2 * HL;              // 12 output cells in x
constexpr int TJ = BJ + 2 * HL;              // 12 output cells in y
constexpr int TK = BK + 2 * HL;              // 36 output cells in z (div by 4)
constexpr int TJS = TJ - 1;                  // 11 storable b-rows
constexpr int TKS = TK - 1;                  // 35 storable c-slots
constexpr int TBINS = TI * TJS * TKS;        // 4620 u64 = 36.96 KB

constexpr float SCALE     = 512.0f;          // 2^9
constexpr float INV_SCALE = 1.0f / 512.0f;

__device__ __forceinline__ unsigned long long pack4(float fa, float fb, float fc, float fd) {
    const int d0 = (int)rintf(fa * SCALE);
    const int d1 = (int)rintf(fb * SCALE);
    const int d2 = (int)rintf(fc * SCALE);
    const int d3 = (int)rintf(fd * SCALE);
    const int lo = d0 + (d1 << 16);
    const int hi = d2 + (d3 << 16) - (lo < 0 ? 1 : 0);
    return ((unsigned long long)(unsigned)hi << 32) | (unsigned)lo;
}

__device__ __forceinline__ void decode4(unsigned long long T,
                                        int& e0, int& e1, int& e2, int& e3) {
    const int lo = (int)(unsigned)T;
    const int hi = (int)(unsigned)(T >> 32) + (lo < 0 ? 1 : 0);
    e0 = (int)(short)(unsigned short)lo;
    e1 = (lo - e0) >> 16;
    e2 = (int)(short)(unsigned short)hi;
    e3 = (hi - e2) >> 16;
}

__global__ __launch_bounds__(512, 8) void splat_corner_kernel(const float* __restrict__ src,
                                                              const float* __restrict__ flow,
                                                              float* __restrict__ out) {
    __shared__ __align__(16) unsigned long long bins[TBINS];

    const int t  = threadIdx.x;
    const int bk = blockIdx.x, bj = blockIdx.y, bi = blockIdx.z;
    const int i0 = bi * BI, j0 = bj * BJ, k0 = bk * BK;
    const int xg0 = i0 - HL, yg0 = j0 - HL, zg0 = k0 - HL;  // tile origin (global)

    // --- zero bins (4620 u64 = 2310 float4) ---
    {
        const float4 z4 = make_float4(0.f, 0.f, 0.f, 0.f);
        float4* b4 = reinterpret_cast<float4*>(bins);
        for (int c = t; c < TBINS * 2 / 4; c += 512) b4[c] = z4;
    }
    __syncthreads();

    // --- scatter: 2048 voxels, 4 consecutive-z voxels per thread ---
    {
        const int kg = (t & 7) * 4;            // 0..28 (128B contiguous per row)
        const int cj = (t >> 3) & 7;
        const int ci = t >> 6;                 // 0..7
        const int i = i0 + ci, j = j0 + cj, k = k0 + kg;
        const int off = i * WD + j * Dd + k;

        const float4 s4  = *reinterpret_cast<const float4*>(src + off);
        const float4 fx4 = *reinterpret_cast<const float4*>(flow + off);
        const float4 fy4 = *reinterpret_cast<const float4*>(flow + N + off);
        const float4 fz4 = *reinterpret_cast<const float4*>(flow + 2 * N + off);

        const float sa[4]  = {s4.x, s4.y, s4.z, s4.w};
        const float fxa[4] = {fx4.x, fx4.y, fx4.z, fx4.w};
        const float fya[4] = {fy4.x, fy4.y, fy4.z, fy4.w};
        const float fza[4] = {fz4.x, fz4.y, fz4.z, fz4.w};

#pragma unroll
        for (int q = 0; q < 4; ++q) {
            const float lx = fmaxf((float)i       + fxa[q], 0.0f);
            const float ly = fmaxf((float)j       + fya[q], 0.0f);
            const float lz = fmaxf((float)(k + q) + fza[q], 0.0f);

            const float bx = floorf(lx), by = floorf(ly), bz = floorf(lz);
            const float dx = lx - bx,    dy = ly - by,    dz = lz - bz;

            const int x0 = min((int)bx, H - 1);
            const int y0 = min((int)by, W - 1);
            const int z0 = min((int)bz, Dd - 1);
            const int x1 = min(x0 + 1, H - 1);
            const int y1 = min(y0 + 1, W - 1);
            const int z1 = min(z0 + 1, Dd - 1);

            const float s = sa[q];
            // collapse handling: coincident corners -> fold factor 0 deposits
            // full weight into the clamped cell (reference's double-add).
            const float dyf = (y1 > y0) ? dy : 0.0f;
            const float dzf = (z1 > z0) ? dz : 0.0f;

            const int a0 = x0 - xg0, a1 = x1 - xg0;
            const int b0 = y0 - yg0;
            const int c0 = z0 - zg0;

            const bool fast = ((unsigned)a0 < (unsigned)TI) & ((unsigned)a1 < (unsigned)TI) &
                              ((unsigned)b0 < (unsigned)TJS) &
                              ((unsigned)c0 < (unsigned)TKS);

            if (__builtin_expect(fast, 1)) {
                const float w0 = s * (1.0f - dx);     // x0-corner row weight
                const float w1 = s * dx;              // x1-corner row weight
                // corner fields: m1=w*dy, m2=w*dz, FD=m1*dz, FB=m1-FD,
                // FC=m2-FD, FA=(w-m1)-FC
                {
                    const float m1 = w0 * dyf, m2 = w0 * dzf;
                    const float FD = m1 * dzf;
                    const float FB = m1 - FD, FC = m2 - FD;
                    const float FA = (w0 - m1) - FC;
                    atomicAdd(&bins[(a0 * TJS + b0) * TKS + c0], pack4(FA, FB, FC, FD));
                }
                {
                    const float m1 = w1 * dyf, m2 = w1 * dzf;
                    const float FD = m1 * dzf;
                    const float FB = m1 - FD, FC = m2 - FD;
                    const float FA = (w1 - m1) - FC;
                    atomicAdd(&bins[(a1 * TJS + b0) * TKS + c0], pack4(FA, FB, FC, FD));
                }
            } else {
                // rare outlier: direct global f32 atomics (exact corner semantics)
                const float wx0 = 1.0f - dx, wy0 = 1.0f - dy, wz0 = 1.0f - dz;
                const float a00 = s * wx0 * wy0;
                const float a01 = s * wx0 * dy;
                const float a10 = s * dx * wy0;
                const float a11 = s * dx * dy;
                unsafeAtomicAdd(out + x0 * WD + y0 * Dd + z0, a00 * wz0);
                unsafeAtomicAdd(out + x0 * WD + y0 * Dd + z1, a00 * dz);
                unsafeAtomicAdd(out + x0 * WD + y1 * Dd + z0, a01 * wz0);
                unsafeAtomicAdd(out + x0 * WD + y1 * Dd + z1, a01 * dz);
                unsafeAtomicAdd(out + x1 * WD + y0 * Dd + z0, a10 * wz0);
                unsafeAtomicAdd(out + x1 * WD + y0 * Dd + z1, a10 * dz);
                unsafeAtomicAdd(out + x1 * WD + y1 * Dd + z0, a11 * wz0);
                unsafeAtomicAdd(out + x1 * WD + y1 * Dd + z1, a11 * dz);
            }
        }
    }
    __syncthreads();

    // --- flush: z-aligned quads of 4 cells/thread (TK=36, 9 quads/row);
    //     one field per covering bin, bins shared across the quad ---
    for (int qd = t; qd < TI * TJ * (TK / 4); qd += 512) {
        const int qz  = qd % (TK / 4);
        const int row = qd / (TK / 4);
        const int b   = row % TJ;          // cell-row y, 0..11
        const int a   = row / TJ;          // cell-row x, 0..11
        const int z0q = qz * 4;

        const bool hb = (b < TJS);         // row b has stored bins
        const bool hm = (b > 0);           // row b-1 has stored bins
        const unsigned long long* rb = bins + (a * TJS + b) * TKS;
        const unsigned long long* rm = rb - TKS;

        unsigned long long vb[5], vm[5];
#pragma unroll
        for (int d = 0; d < 5; ++d) {
            const int zi = z0q - 1 + d;
            const bool zok = ((unsigned)zi < (unsigned)TKS);
            vb[d] = (hb && zok) ? rb[zi] : 0ull;
            vm[d] = (hm && zok) ? rm[zi] : 0ull;
        }
        if ((vb[0] | vb[1] | vb[2] | vb[3] | vb[4] |
             vm[0] | vm[1] | vm[2] | vm[3] | vm[4]) == 0ull) continue;

        int A[5], C[5], B[5], D[5];
#pragma unroll
        for (int d = 0; d < 5; ++d) {
            int e0, e1, e2, e3;
            decode4(vb[d], e0, e1, e2, e3);
            A[d] = e0; C[d] = e2;
            decode4(vm[d], e0, e1, e2, e3);
            B[d] = e1; D[d] = e3;
        }

        const int x = xg0 + a, y = yg0 + b;
        const bool xyok = ((unsigned)x < (unsigned)H) & ((unsigned)y < (unsigned)W);
        float* orow = out + x * WD + y * Dd;

#pragma unroll
        for (int zz = 0; zz < 4; ++zz) {
            const int vi = A[zz + 1] + B[zz + 1] + C[zz] + D[zz];
            const int zglob = zg0 + z0q + zz;
            if (vi != 0 && xyok && (unsigned)zglob < (unsigned)Dd) {
                unsafeAtomicAdd(orow + zglob, (float)vi * INV_SCALE);
            }
        }
    }
}

extern "C" void kernel_launch(void* const* d_in, const int* in_sizes, int n_in,
                              void* d_out, int out_size, void* d_ws, size_t ws_size,
                              hipStream_t stream) {
    const float* src  = (const float*)d_in[0];
    const float* flow = (const float*)d_in[1];
    float* out = (float*)d_out;

    // Harness poisons d_out once and never re-poisons between replays: zero it every call.
    hipMemsetAsync(out, 0, (size_t)N * sizeof(float), stream);

    const dim3 block(512);
    const dim3 grid(Dd / BK, W / BJ, H / BI);  // (6, 24, 24) = 3456 blocks
    splat_corner_kernel<<<grid, block, 0, stream>>>(src, flow, out);
}

// Round 12
// 130.695 us; speedup vs baseline: 2.0242x; 2.0242x over previous
//
#include <hip/hip_runtime.h>

// Trilinear forward-splat, corner-basis LDS accumulation, 4x16-bit packed u64
// atomics (2 DS atomics/voxel), R9-style coalesced per-cell flush.
// R11->R12: the quad flush (lane-stride-4 atomics) was the WRITE_SIZE x2.5
// amplifier in BOTH R10 and R11 (241/249 MB vs R9's 99). Restore R9's
// consecutive-lane = consecutive-z per-cell flush; keep corner-basis fields
// (one field per covering bin: ~12 VALU/cell vs R9's ~36).
// Reference semantics (exact):
//   locs = max(grid + flow, 0)
//   delta = locs - floor(locs)           (from UNclamped floor)
//   base  = min((int)floor(locs), dim-1)
//   corner per axis = min(base + {0,1}, dim-1)   (collapsed corners add twice)
//
// Per x-corner deposit into bin (a,b0,c0), fields scale 2^9 fixed-point:
//   F_A=w(1-dy)(1-dz) -> cell(b0,c0);     F_B=w*dy(1-dz) -> cell(b0+1,c0)
//   F_C=w(1-dy)dz     -> cell(b0,c0+1);   F_D=w*dy*dz    -> cell(b0+1,c0+1)
// cell(b,z) = e0[bin(b,z)] + e1[bin(b-1,z)] + e2[bin(b,z-1)] + e3[bin(b-1,z-1)]
// Modular u64 sums exact while |field sum| < 2^15 and |lo-word sum| < 2^31.

constexpr int H = 192, W = 192, Dd = 192;
constexpr int N = H * W * Dd;
constexpr int WD = W * Dd;

constexpr int BI = 8, BJ = 8, BK = 32;       // source chunk per block (2048 voxels)
constexpr int HL = 2;                        // halo radius
constexpr int TI = BI + 2 * HL;              // 12 output cells in x
constexpr int TJ = BJ + 2 * HL;              // 12 output cells in y
constexpr int TK = BK + 2 * HL;              // 36 output cells in z
constexpr int TJS = TJ - 1;                  // 11 storable b-rows (b=TJ-1 never written)
constexpr int TKS = TK - 1;                  // 35 storable c-slots
constexpr int TBINS = TI * TJS * TKS;        // 4620 u64 = 36.96 KB

constexpr float SCALE     = 512.0f;          // 2^9
constexpr float INV_SCALE = 1.0f / 512.0f;

__device__ __forceinline__ unsigned long long pack4(float fa, float fb, float fc, float fd) {
    const int d0 = (int)rintf(fa * SCALE);
    const int d1 = (int)rintf(fb * SCALE);
    const int d2 = (int)rintf(fc * SCALE);
    const int d3 = (int)rintf(fd * SCALE);
    const int lo = d0 + (d1 << 16);
    const int hi = d2 + (d3 << 16) - (lo < 0 ? 1 : 0);
    return ((unsigned long long)(unsigned)hi << 32) | (unsigned)lo;
}

// single-field extracts (borrow-corrected)
__device__ __forceinline__ int fld0(unsigned long long T) {   // F_A
    return (int)(short)(unsigned short)(unsigned)T;
}
__device__ __forceinline__ int fld1(unsigned long long T) {   // F_B
    const int lo = (int)(unsigned)T;
    return (lo - (int)(short)(unsigned short)lo) >> 16;
}
__device__ __forceinline__ int fld2(unsigned long long T) {   // F_C
    const int lo = (int)(unsigned)T;
    const int hi = (int)(unsigned)(T >> 32) + (lo < 0 ? 1 : 0);
    return (int)(short)(unsigned short)hi;
}
__device__ __forceinline__ int fld3(unsigned long long T) {   // F_D
    const int lo = (int)(unsigned)T;
    const int hi = (int)(unsigned)(T >> 32) + (lo < 0 ? 1 : 0);
    return (hi - (int)(short)(unsigned short)hi) >> 16;
}

__global__ __launch_bounds__(512, 8) void splat_corner2_kernel(const float* __restrict__ src,
                                                               const float* __restrict__ flow,
                                                               float* __restrict__ out) {
    __shared__ __align__(16) unsigned long long bins[TBINS];

    const int t  = threadIdx.x;
    const int bk = blockIdx.x, bj = blockIdx.y, bi = blockIdx.z;
    const int i0 = bi * BI, j0 = bj * BJ, k0 = bk * BK;
    const int xg0 = i0 - HL, yg0 = j0 - HL, zg0 = k0 - HL;  // tile origin (global)

    // --- zero bins (4620 u64 = 2310 float4) ---
    {
        const float4 z4 = make_float4(0.f, 0.f, 0.f, 0.f);
        float4* b4 = reinterpret_cast<float4*>(bins);
        for (int c = t; c < TBINS * 2 / 4; c += 512) b4[c] = z4;
    }
    __syncthreads();

    // --- scatter: 2048 voxels, 4 consecutive-z voxels per thread ---
    {
        const int kg = (t & 7) * 4;            // 0..28 (128B contiguous per row)
        const int cj = (t >> 3) & 7;
        const int ci = t >> 6;                 // 0..7
        const int i = i0 + ci, j = j0 + cj, k = k0 + kg;
        const int off = i * WD + j * Dd + k;

        const float4 s4  = *reinterpret_cast<const float4*>(src + off);
        const float4 fx4 = *reinterpret_cast<const float4*>(flow + off);
        const float4 fy4 = *reinterpret_cast<const float4*>(flow + N + off);
        const float4 fz4 = *reinterpret_cast<const float4*>(flow + 2 * N + off);

        const float sa[4]  = {s4.x, s4.y, s4.z, s4.w};
        const float fxa[4] = {fx4.x, fx4.y, fx4.z, fx4.w};
        const float fya[4] = {fy4.x, fy4.y, fy4.z, fy4.w};
        const float fza[4] = {fz4.x, fz4.y, fz4.z, fz4.w};

#pragma unroll
        for (int q = 0; q < 4; ++q) {
            const float lx = fmaxf((float)i       + fxa[q], 0.0f);
            const float ly = fmaxf((float)j       + fya[q], 0.0f);
            const float lz = fmaxf((float)(k + q) + fza[q], 0.0f);

            const float bx = floorf(lx), by = floorf(ly), bz = floorf(lz);
            const float dx = lx - bx,    dy = ly - by,    dz = lz - bz;

            const int x0 = min((int)bx, H - 1);
            const int y0 = min((int)by, W - 1);
            const int z0 = min((int)bz, Dd - 1);
            const int x1 = min(x0 + 1, H - 1);
            const int y1 = min(y0 + 1, W - 1);
            const int z1 = min(z0 + 1, Dd - 1);

            const float s = sa[q];
            // collapse handling: coincident corners -> fold factor 0 deposits
            // full weight into the clamped cell (reference's double-add).
            const float dyf = (y1 > y0) ? dy : 0.0f;
            const float dzf = (z1 > z0) ? dz : 0.0f;

            const int a0 = x0 - xg0, a1 = x1 - xg0;
            const int b0 = y0 - yg0;
            const int c0 = z0 - zg0;

            const bool fast = ((unsigned)a0 < (unsigned)TI) & ((unsigned)a1 < (unsigned)TI) &
                              ((unsigned)b0 < (unsigned)TJS) &
                              ((unsigned)c0 < (unsigned)TKS);

            if (__builtin_expect(fast, 1)) {
                const float w0 = s * (1.0f - dx);     // x0-corner row weight
                const float w1 = s * dx;              // x1-corner row weight
                {
                    const float m1 = w0 * dyf, m2 = w0 * dzf;
                    const float FD = m1 * dzf;
                    const float FB = m1 - FD, FC = m2 - FD;
                    const float FA = (w0 - m1) - FC;
                    atomicAdd(&bins[(a0 * TJS + b0) * TKS + c0], pack4(FA, FB, FC, FD));
                }
                {
                    const float m1 = w1 * dyf, m2 = w1 * dzf;
                    const float FD = m1 * dzf;
                    const float FB = m1 - FD, FC = m2 - FD;
                    const float FA = (w1 - m1) - FC;
                    atomicAdd(&bins[(a1 * TJS + b0) * TKS + c0], pack4(FA, FB, FC, FD));
                }
            } else {
                // rare outlier: direct global f32 atomics (exact corner semantics)
                const float wx0 = 1.0f - dx, wy0 = 1.0f - dy, wz0 = 1.0f - dz;
                const float a00 = s * wx0 * wy0;
                const float a01 = s * wx0 * dy;
                const float a10 = s * dx * wy0;
                const float a11 = s * dx * dy;
                unsafeAtomicAdd(out + x0 * WD + y0 * Dd + z0, a00 * wz0);
                unsafeAtomicAdd(out + x0 * WD + y0 * Dd + z1, a00 * dz);
                unsafeAtomicAdd(out + x0 * WD + y1 * Dd + z0, a01 * wz0);
                unsafeAtomicAdd(out + x0 * WD + y1 * Dd + z1, a01 * dz);
                unsafeAtomicAdd(out + x1 * WD + y0 * Dd + z0, a10 * wz0);
                unsafeAtomicAdd(out + x1 * WD + y0 * Dd + z1, a10 * dz);
                unsafeAtomicAdd(out + x1 * WD + y1 * Dd + z0, a11 * wz0);
                unsafeAtomicAdd(out + x1 * WD + y1 * Dd + z1, a11 * dz);
            }
        }
    }
    __syncthreads();

    // --- flush: per-cell, consecutive lanes -> consecutive z (coalesced
    //     atomics, ~4B/atomic HBM cost). One field per covering bin. ---
    for (int c = t; c < TI * TJ * TK; c += 512) {
        const int z    = c % TK;           // 0..35
        const int rest = c / TK;
        const int b    = rest % TJ;        // 0..11
        const int a    = rest / TJ;        // 0..11

        const int rb = (a * TJS + b) * TKS;      // row b base (valid if b<TJS)
        const int rm = rb - TKS;                 // row b-1 base (valid if b>0)
        const bool hb = (b < TJS), hm = (b > 0);
        const bool hz = (z < TKS), hzm = (z > 0);

        const unsigned long long Tb  = (hb && hz)  ? bins[rb + z]     : 0ull;
        const unsigned long long Tm  = (hm && hz)  ? bins[rm + z]     : 0ull;
        const unsigned long long Tbz = (hb && hzm) ? bins[rb + z - 1] : 0ull;
        const unsigned long long Tmz = (hm && hzm) ? bins[rm + z - 1] : 0ull;

        if ((Tb | Tm | Tbz | Tmz) == 0ull) continue;

        const int vi = fld0(Tb) + fld1(Tm) + fld2(Tbz) + fld3(Tmz);
        if (vi != 0) {
            const int x = xg0 + a, y = yg0 + b, zz = zg0 + z;
            if (((unsigned)x < (unsigned)H) & ((unsigned)y < (unsigned)W) &
                ((unsigned)zz < (unsigned)Dd)) {
                unsafeAtomicAdd(out + x * WD + y * Dd + zz, (float)vi * INV_SCALE);
            }
        }
    }
}

extern "C" void kernel_launch(void* const* d_in, const int* in_sizes, int n_in,
                              void* d_out, int out_size, void* d_ws, size_t ws_size,
                              hipStream_t stream) {
    const float* src  = (const float*)d_in[0];
    const float* flow = (const float*)d_in[1];
    float* out = (float*)d_out;

    // Harness poisons d_out once and never re-poisons between replays: zero it every call.
    hipMemsetAsync(out, 0, (size_t)N * sizeof(float), stream);

    const dim3 block(512);
    const dim3 grid(Dd / BK, W / BJ, H / BI);  // (6, 24, 24) = 3456 blocks
    splat_corner2_kernel<<<grid, block, 0, stream>>>(src, flow, out);
}